// Round 7
// baseline (481.720 us; speedup 1.0000x reference)
//
#include <hip/hip_runtime.h>
#include <math.h>

constexpr int NN = 4096, DD = 64, TT = 60, HH = 128, GG = 512, KK = 192;

typedef _Float16 h8 __attribute__((ext_vector_type(8)));
typedef float f4 __attribute__((ext_vector_type(4)));

// ws layout (float offsets)
constexpr size_t XNT = 0;                                  // half [T][N][D] RAW x fp16; REUSED later as swizzled hbn16
constexpr size_t WFRG = (size_t)TT * NN * DD / 2;          // half [w][g][ks][lane][8] = 98304 halves
constexpr size_t BSUM = WFRG + 98304 / 2;                  // [512] f32 (unused now, layout keeper)
constexpr size_t SC1 = BSUM + GG;                          // [64]
constexpr size_t SH1 = SC1 + DD;                           // [64]
constexpr size_t HID = SH1 + DD;                           // [N][H] f32
constexpr size_t HBN = HID + (size_t)NN * HH;              // [N][H]
constexpr size_t SC2 = HBN + (size_t)NN * HH;              // [128]
constexpr size_t SH2 = SC2 + HH;
constexpr size_t U1O = SH2 + HH;
constexpr size_t U2O = U1O + HH;
constexpr size_t CCO = U2O + HH;                           // [4]: c1, c2, s1max(encoded uint)
constexpr size_t S1O = CCO + 4;                            // [N]
constexpr size_t S2O = S1O + NN;
constexpr size_t H2O = S2O + NN;                           // [N][H] (unused now)
constexpr size_t SSUM = H2O + (size_t)NN * HH;             // [0:64) bn1 sum, [64:128) bn1 sumsq,
                                                           // 128 bn1 ctr, 129 bn2 ctr,
                                                           // [132:260) bn2 sum, [260:388) bn2 sumsq

__device__ __forceinline__ float sigmoidf_(float x) { return 1.f / (1.f + __expf(-x)); }
__device__ __forceinline__ float tanhfast_(float x) { return 1.f - 2.f / (__expf(2.f * x) + 1.f); }
__device__ __forceinline__ float leakyf_(float z) { return fmaxf(z, 0.01f * z); }

__device__ __forceinline__ unsigned fenc_(float f) {
    unsigned b = __float_as_uint(f);
    return (b & 0x80000000u) ? ~b : (b | 0x80000000u);
}
__device__ __forceinline__ float fdec_(unsigned u) {
    return (u & 0x80000000u) ? __uint_as_float(u & 0x7fffffffu) : __uint_as_float(~u);
}

union HU { unsigned u; _Float16 h[2]; };

// ---- k_pre: blocks [0,1024) = BN1 stats + coalesced fp16 transpose of x;
//             blocks [1024,1408) = weight fragment swizzle (NO sc1 fold);
//             block 1408 = u/v/c attention prep ----
__global__ __launch_bounds__(256) void k_pre(const float* __restrict__ x,
                                             const float* __restrict__ g1,
                                             const float* __restrict__ b1,
                                             const float* __restrict__ Wih,
                                             const float* __restrict__ Whh,
                                             const float* __restrict__ Wt,
                                             const float* __restrict__ bt,
                                             const float* __restrict__ a,
                                             float* __restrict__ ws) {
    int b = blockIdx.x;
    int tid = threadIdx.x;
    if (b >= 1024) {
        if (b == 1408) {
            int k = tid;
            if (k < HH) {
                float u1 = 0.f, u2 = 0.f;
                for (int j = 0; j < HH; j++) {
                    float w = Wt[j * HH + k];
                    u1 = fmaf(w, a[j], u1);
                    u2 = fmaf(w, a[HH + j], u2);
                }
                ws[U1O + k] = u1;
                ws[U2O + k] = u2;
                if (k == 0) {
                    float c1 = 0.f, c2 = 0.f;
                    for (int j = 0; j < HH; j++) {
                        c1 = fmaf(bt[j], a[j], c1);
                        c2 = fmaf(bt[j], a[HH + j], c2);
                    }
                    ws[CCO] = c1;
                    ws[CCO + 1] = c2;
                    ((unsigned*)ws)[CCO + 2] = fenc_(-1e30f);
                }
            }
            return;
        }
        // weight swizzle: frag (w,g,ks): W[k][col], col=g*128+w*16+(lane&15), k=ks*32+(lane>>4)*8+j
        int o = (b - 1024) * 256 + tid;
        _Float16* wf = (_Float16*)(ws + WFRG);
        int j = o & 7;
        int lane = (o >> 3) & 63;
        int rest = o >> 9;
        int ks = rest % 6;
        int gw = rest / 6;
        int g = gw & 3, w = gw >> 2;
        int col = g * 128 + w * 16 + (lane & 15);
        int k = ks * 32 + (lane >> 4) * 8 + j;
        float v = (k < DD) ? Wih[col * DD + k] : Whh[col * HH + (k - DD)];
        wf[o] = (_Float16)v;
        return;
    }
    // ---- xstats: rows n0..n0+3 (15360 floats, fully coalesced) ----
    __shared__ _Float16 lx[256 * 66];   // [k=r*64+d][t], stride 66 (bank-spread)
    __shared__ float rs[256], rss[256];
    __shared__ unsigned done;
    const float4* xb = (const float4*)(x + (size_t)b * 15360);
#pragma unroll
    for (int q = 0; q < 15; q++) {
        int f = q * 256 + tid;
        float4 v = xb[f];
        int k = f / 15, sI = f - k * 15;
        HU p0, p1;
        p0.h[0] = (_Float16)v.x; p0.h[1] = (_Float16)v.y;
        p1.h[0] = (_Float16)v.z; p1.h[1] = (_Float16)v.w;
        *(unsigned*)&lx[k * 66 + sI * 4] = p0.u;
        *(unsigned*)&lx[k * 66 + sI * 4 + 2] = p1.u;
    }
    __syncthreads();
    {
        int r = tid >> 6, d = tid & 63;
        const _Float16* rowp = &lx[(r * 64 + d) * 66];
        float s = 0.f, ss = 0.f;
#pragma unroll
        for (int t = 0; t < 60; t += 2) {
            HU z; z.u = *(const unsigned*)&rowp[t];
            float v0 = (float)z.h[0], v1 = (float)z.h[1];
            s += v0 + v1;
            ss = fmaf(v0, v0, fmaf(v1, v1, ss));
        }
        rs[tid] = s; rss[tid] = ss;
    }
    __syncthreads();
    if (tid < 64) {
        float ts = rs[tid] + rs[64 + tid] + rs[128 + tid] + rs[192 + tid];
        float tss = rss[tid] + rss[64 + tid] + rss[128 + tid] + rss[192 + tid];
        atomicAdd(&ws[SSUM + tid], ts);
        atomicAdd(&ws[SSUM + 64 + tid], tss);
    }
    __threadfence();
    __syncthreads();
    if (tid == 0) done = atomicAdd((unsigned*)(ws + SSUM) + 128, 1u);
    __syncthreads();
    if (done == 1023u) {
        __threadfence();
        if (tid < 64) {
            float cnt = (float)(NN * TT);
            float m = ws[SSUM + tid] / cnt;
            float var = ws[SSUM + 64 + tid] / cnt - m * m;
            float sc = g1[tid] * rsqrtf(var + 1e-5f);
            ws[SC1 + tid] = sc;
            ws[SH1 + tid] = b1[tid] - m * sc;
        }
    }
    // coalesced fp16 write-out: xnT[t][n0+r][d]
    _Float16* outp = (_Float16*)ws;
    int n0 = b * 4;
    for (int p = tid; p < 1920; p += 256) {
        int t = p >> 5, i = p & 31;
        int kbase = (i >> 3) * 64 + (i & 7) * 8;
        h8 tmp;
#pragma unroll
        for (int u = 0; u < 8; u++) tmp[u] = lx[(kbase + u) * 66 + t];
        *(h8*)(outp + ((size_t)t * NN + n0) * DD + i * 8) = tmp;
    }
}

// ---- LSTM: MFMA, weights persistent in VGPRs (sc1 fold + bias fold in prologue);
//      epilogue: HID write + BN2 partial sums + last-block BN2 finalize ----
__global__ __launch_bounds__(512, 1) void k_lstm(const float* __restrict__ Wih,
                                                 const float* __restrict__ bih,
                                                 const float* __restrict__ bhh,
                                                 const float* __restrict__ g2,
                                                 const float* __restrict__ b2,
                                                 float* __restrict__ ws) {
    int tid = threadIdx.x;
    int w = tid >> 6, lane = tid & 63;
    int quad = lane >> 4, m = lane & 15;
    int r0 = blockIdx.x * 16;
    __shared__ _Float16 hlds[2][16][136];
    __shared__ float sh1s[64];
    __shared__ float biasl[512];
    __shared__ unsigned dn;
    const _Float16* wf = (const _Float16*)(ws + WFRG);

    h8 bw[4][6];
#pragma unroll
    for (int g = 0; g < 4; g++)
#pragma unroll
        for (int ks = 0; ks < 6; ks++)
            bw[g][ks] = *(const h8*)(wf + ((((w * 4 + g) * 6 + ks) * 64 + lane) * 8));

    if (tid < 64) sh1s[tid] = ws[SH1 + tid];
    for (int p = tid; p < 2 * 16 * 136; p += 512) ((_Float16*)hlds)[p] = (_Float16)0.f;
    __syncthreads();

    // fold sc1 into the x-part (ks 0,1) of the B fragments
    {
        int base = (lane >> 4) * 8;
#pragma unroll
        for (int ks = 0; ks < 2; ks++)
#pragma unroll
            for (int j = 0; j < 8; j++) {
                float sc = ws[SC1 + ks * 32 + base + j];
#pragma unroll
                for (int g = 0; g < 4; g++)
                    bw[g][ks][j] = (_Float16)((float)bw[g][ks][j] * sc);
            }
    }
    // bias fold: biasl[c] = bih[c]+bhh[c] + Wih[c,:]·sh1
    {
        int c = tid;
        float bsum = bih[c] + bhh[c];
        const float4* wr = (const float4*)(Wih + c * 64);
#pragma unroll
        for (int q = 0; q < 16; q++) {
            float4 wv = wr[q];
            bsum = fmaf(wv.x, sh1s[q * 4], fmaf(wv.y, sh1s[q * 4 + 1],
                   fmaf(wv.z, sh1s[q * 4 + 2], fmaf(wv.w, sh1s[q * 4 + 3], bsum))));
        }
        biasl[c] = bsum;
    }
    __syncthreads();
    float bias[4];
#pragma unroll
    for (int g = 0; g < 4; g++) bias[g] = biasl[g * 128 + w * 16 + m];

    f4 cst = {};
    float hv[4];
    const _Float16* xb = (const _Float16*)ws + (size_t)(r0 + m) * DD + quad * 8;

    h8 ax0 = *(const h8*)xb;
    h8 ax1 = *(const h8*)(xb + 32);

    for (int t = 0; t < TT; t++) {
        h8 ah[4];
        const _Float16* hb = &hlds[(t + 1) & 1][m][quad * 8];
#pragma unroll
        for (int ks = 0; ks < 4; ks++) ah[ks] = *(const h8*)(hb + ks * 32);
        h8 nx0 = {}, nx1 = {};
        if (t + 1 < TT) {
            const _Float16* xp = xb + (size_t)(t + 1) * NN * DD;
            nx0 = *(const h8*)xp;
            nx1 = *(const h8*)(xp + 32);
        }

        f4 acc[4];
#pragma unroll
        for (int g = 0; g < 4; g++) acc[g] = (f4){bias[g], bias[g], bias[g], bias[g]};
#pragma unroll
        for (int g = 0; g < 4; g++) acc[g] = __builtin_amdgcn_mfma_f32_16x16x32_f16(ax0, bw[g][0], acc[g], 0, 0, 0);
#pragma unroll
        for (int g = 0; g < 4; g++) acc[g] = __builtin_amdgcn_mfma_f32_16x16x32_f16(ax1, bw[g][1], acc[g], 0, 0, 0);
#pragma unroll
        for (int ks = 0; ks < 4; ks++)
#pragma unroll
            for (int g = 0; g < 4; g++)
                acc[g] = __builtin_amdgcn_mfma_f32_16x16x32_f16(ah[ks], bw[g][ks + 2], acc[g], 0, 0, 0);

#pragma unroll
        for (int r = 0; r < 4; r++) {
            float ig = sigmoidf_(acc[0][r]);
            float fg = sigmoidf_(acc[1][r]);
            float gg = tanhfast_(acc[2][r]);
            float og = sigmoidf_(acc[3][r]);
            float c = fmaf(fg, cst[r], ig * gg);
            cst[r] = c;
            hv[r] = og * tanhfast_(c);
        }
        _Float16* wbuf = &hlds[t & 1][0][0];
        int col = w * 16 + m;
#pragma unroll
        for (int r = 0; r < 4; r++) wbuf[(quad * 4 + r) * 136 + col] = (_Float16)hv[r];
        __syncthreads();
        ax0 = nx0; ax1 = nx1;
    }
    int col = w * 16 + m;
#pragma unroll
    for (int r = 0; r < 4; r++)
        ws[HID + (size_t)(r0 + quad * 4 + r) * HH + col] = hv[r];

    // BN2 partial sums (wave-local reduce over the 16 rows, then 1 atomic/col)
    float s = hv[0] + hv[1] + hv[2] + hv[3];
    float ss = fmaf(hv[0], hv[0], fmaf(hv[1], hv[1], fmaf(hv[2], hv[2], hv[3] * hv[3])));
    s += __shfl_xor(s, 16, 64); s += __shfl_xor(s, 32, 64);
    ss += __shfl_xor(ss, 16, 64); ss += __shfl_xor(ss, 32, 64);
    if (quad == 0) {
        atomicAdd(&ws[SSUM + 132 + col], s);
        atomicAdd(&ws[SSUM + 260 + col], ss);
    }
    __threadfence();
    __syncthreads();
    if (tid == 0) dn = atomicAdd((unsigned*)(ws + SSUM) + 129, 1u);
    __syncthreads();
    if (dn == 255u) {
        __threadfence();
        if (tid < 128) {
            float mm = ws[SSUM + 132 + tid] / (float)NN;
            float var = ws[SSUM + 260 + tid] / (float)NN - mm * mm;
            float sc = g2[tid] * rsqrtf(var + 1e-5f);
            ws[SC2 + tid] = sc;
            ws[SH2 + tid] = b2[tid] - mm * sc;
        }
    }
}

// ---- apply BN2: s1, s2, fp32 hbn, LDS-staged coalesced swizzled fp16 hbn, s1max ----
__global__ void k_hbn(float* __restrict__ ws) {
    __shared__ float sc[HH], sh[HH], u1s[HH], u2s[HH];
    __shared__ _Float16 swz[4096];
    int tid = threadIdx.x;
    if (tid < HH) {
        sc[tid] = ws[SC2 + tid]; sh[tid] = ws[SH2 + tid];
        u1s[tid] = ws[U1O + tid]; u2s[tid] = ws[U2O + tid];
    }
    __syncthreads();
    int r = tid >> 3, l = tid & 7;
    int n = blockIdx.x * 32 + r;
    const float* hr = ws + HID + (size_t)n * HH;
    float* hb = ws + HBN + (size_t)n * HH;
    int lanehi = (r >> 3);
    int jj = r & 7;
    float d1 = 0.f, d2 = 0.f;
    int k0 = l * 16;
#pragma unroll
    for (int q4 = 0; q4 < 4; q4++) {
        float4 hv4 = *(const float4*)&hr[k0 + q4 * 4];
        float4 o;
#pragma unroll
        for (int c = 0; c < 4; c++) {
            int kk = k0 + q4 * 4 + c;
            float v = fmaf(((const float*)&hv4)[c], sc[kk], sh[kk]);
            ((float*)&o)[c] = v;
            swz[l * 512 + (lanehi * 16 + (kk & 15)) * 8 + jj] = (_Float16)v;
            d1 = fmaf(v, u1s[kk], d1);
            d2 = fmaf(v, u2s[kk], d2);
        }
        *(float4*)&hb[k0 + q4 * 4] = o;
    }
#pragma unroll
    for (int o = 1; o < 8; o <<= 1) { d1 += __shfl_xor(d1, o, 64); d2 += __shfl_xor(d2, o, 64); }
    if (l == 0) {
        float s1 = d1 + ws[CCO];
        ws[S1O + n] = s1;
        ws[S2O + n] = d2 + ws[CCO + 1];
        atomicMax((unsigned*)ws + CCO + 2, fenc_(s1));
    }
    __syncthreads();
    _Float16* dst = (_Float16*)ws + (size_t)blockIdx.x * 4096;
    for (int p = tid; p < 512; p += 256)
        *(h8*)(dst + p * 8) = *(const h8*)(swz + p * 8);
}

// ---- attention + fc fused: 256 blocks x 512 thr; wave w owns hgroup w;
//      h2 stays in LDS; fc + out-projection + sigmoid in epilogue ----
__global__ __launch_bounds__(512, 1) void k_attfc(const float* __restrict__ Wfc,
                                                  const float* __restrict__ bfc,
                                                  const float* __restrict__ Wout,
                                                  const float* __restrict__ bout,
                                                  float* __restrict__ ws,
                                                  float* __restrict__ out) {
    __shared__ float ls1[NN];
    __shared__ float h2s[16][132];
    int tid = threadIdx.x;
    int w = tid >> 6, lane = tid & 63;
    int quad = lane >> 4, m = lane & 15;
    int n0 = blockIdx.x * 16;
    for (int i = tid; i < NN; i += 512) ls1[i] = ws[S1O + i];
    __syncthreads();
    float s1max = fdec_(((unsigned*)ws)[CCO + 2]);
    float s2n = ws[S2O + n0 + m];
    float mi = leakyf_(s2n + s1max);
    const _Float16* hbsw = (const _Float16*)ws;
    int hg = w;
    f4 acc = {};
    float psum = 0.f;
    h8 bcur = *(const h8*)(hbsw + ((size_t)hg * 64 + lane) * 8);
    for (int jt = 0; jt < 128; jt++) {
        const float* sp = &ls1[jt * 32 + quad * 8];
        h8 ap;
        float ps = 0.f;
#pragma unroll
        for (int jj = 0; jj < 8; jj++) {
            float z = s2n + sp[jj];
            float p = __expf(leakyf_(z) - mi);
            ps += p;
            ap[jj] = (_Float16)p;
        }
        psum += ps;
        int jn = (jt + 1 < 128) ? jt + 1 : 127;
        h8 bnext = *(const h8*)(hbsw + ((size_t)(jn * 8 + hg) * 64 + lane) * 8);
        acc = __builtin_amdgcn_mfma_f32_16x16x32_f16(ap, bcur, acc, 0, 0, 0);
        bcur = bnext;
    }
    psum += __shfl_xor(psum, 16, 64);
    psum += __shfl_xor(psum, 32, 64);
    float pinv = 1.f / psum;   // lane m holds row m's inverse denom
    int h = hg * 16 + m;
#pragma unroll
    for (int r = 0; r < 4; r++) {
        int row = quad * 4 + r;
        float inv = __shfl(pinv, row, 64);
        float hbv = ws[HBN + (size_t)(n0 + row) * HH + h];
        h2s[row][h] = fmaf(acc[r], inv, hbv);
    }
    __syncthreads();
    // fc: row = tid>>5 (16 rows), jj = tid&31; thread does j = jj, jj+32, jj+64, jj+96
    int row = tid >> 5, jj = tid & 31;
    float po = 0.f;
#pragma unroll
    for (int q = 0; q < 4; q++) {
        int j = q * 32 + jj;
        const float4* wr = (const float4*)(Wfc + (size_t)j * HH);
        float a = 0.f;
#pragma unroll 8
        for (int kq = 0; kq < 32; kq++) {
            float4 wv = wr[kq];
            float4 hv = *(const float4*)&h2s[row][kq * 4];
            a = fmaf(wv.x, hv.x, fmaf(wv.y, hv.y, fmaf(wv.z, hv.z, fmaf(wv.w, hv.w, a))));
        }
        po = fmaf(leakyf_(a + bfc[j]), Wout[j], po);
    }
#pragma unroll
    for (int o = 1; o < 32; o <<= 1) po += __shfl_xor(po, o, 64);
    if (jj == 0) out[n0 + row] = 1.f / (1.f + __expf(-(po + bout[0])));
}

extern "C" void kernel_launch(void* const* d_in, const int* in_sizes, int n_in,
                              void* d_out, int out_size, void* d_ws, size_t ws_size,
                              hipStream_t stream) {
    const float* x = (const float*)d_in[0];
    const float* bn1_g = (const float*)d_in[1];
    const float* bn1_b = (const float*)d_in[2];
    const float* W_ih = (const float*)d_in[3];
    const float* W_hh = (const float*)d_in[4];
    const float* b_ih = (const float*)d_in[5];
    const float* b_hh = (const float*)d_in[6];
    const float* bn2_g = (const float*)d_in[7];
    const float* bn2_b = (const float*)d_in[8];
    const float* W_t = (const float*)d_in[9];
    const float* b_t = (const float*)d_in[10];
    const float* a = (const float*)d_in[11];
    const float* W_fc = (const float*)d_in[12];
    const float* b_fc = (const float*)d_in[13];
    const float* W_out = (const float*)d_in[14];
    const float* b_out = (const float*)d_in[15];
    float* ws = (float*)d_ws;
    float* out = (float*)d_out;

    hipMemsetAsync((char*)d_ws + SSUM * sizeof(float), 0, 392 * sizeof(float), stream);
    k_pre<<<1409, 256, 0, stream>>>(x, bn1_g, bn1_b, W_ih, W_hh, W_t, b_t, a, ws);
    k_lstm<<<NN / 16, 512, 0, stream>>>(W_ih, b_ih, b_hh, bn2_g, bn2_b, ws);
    k_hbn<<<NN / 32, 256, 0, stream>>>(ws);
    k_attfc<<<NN / 16, 512, 0, stream>>>(W_fc, b_fc, W_out, b_out, ws, out);
}

// Round 8
// 361.565 us; speedup vs baseline: 1.3323x; 1.3323x over previous
//
#include <hip/hip_runtime.h>
#include <math.h>

constexpr int NN = 4096, DD = 64, TT = 60, HH = 128, GG = 512, KK = 192;

typedef _Float16 h8 __attribute__((ext_vector_type(8)));
typedef float f4 __attribute__((ext_vector_type(4)));

// ws layout (float offsets)
constexpr size_t XNT = 0;                                  // half [T][N][D] RAW x fp16; REUSED later as swizzled hbn16
constexpr size_t WFRG = (size_t)TT * NN * DD / 2;          // half [w][g][ks][lane][8] = 98304 halves
constexpr size_t BSUM = WFRG + 98304 / 2;                  // [512] f32 (layout keeper)
constexpr size_t SC1 = BSUM + GG;                          // [64]
constexpr size_t SH1 = SC1 + DD;                           // [64]
constexpr size_t HID = SH1 + DD;                           // [N][H] f32
constexpr size_t HBN = HID + (size_t)NN * HH;              // [N][H]
constexpr size_t SC2 = HBN + (size_t)NN * HH;              // [128]
constexpr size_t SH2 = SC2 + HH;
constexpr size_t U1O = SH2 + HH;
constexpr size_t U2O = U1O + HH;
constexpr size_t CCO = U2O + HH;                           // [4]: c1, c2, s1max(encoded uint)
constexpr size_t S1O = CCO + 4;                            // [N]
constexpr size_t S2O = S1O + NN;
constexpr size_t H2O = S2O + NN;                           // [N][H] (unused)
constexpr size_t SSUM = H2O + (size_t)NN * HH;             // [0:64) bn1 sum, [64:128) bn1 sumsq,
                                                           // 128 bn1 ctr, 129 bn2 ctr,
                                                           // [132:260) bn2 sum, [260:388) bn2 sumsq

__device__ __forceinline__ float sigmoidf_(float x) { return 1.f / (1.f + __expf(-x)); }
__device__ __forceinline__ float tanhfast_(float x) { return 1.f - 2.f / (__expf(2.f * x) + 1.f); }
__device__ __forceinline__ float leakyf_(float z) { return fmaxf(z, 0.01f * z); }

__device__ __forceinline__ unsigned fenc_(float f) {
    unsigned b = __float_as_uint(f);
    return (b & 0x80000000u) ? ~b : (b | 0x80000000u);
}
__device__ __forceinline__ float fdec_(unsigned u) {
    return (u & 0x80000000u) ? __uint_as_float(u & 0x7fffffffu) : __uint_as_float(~u);
}

constexpr int TSTR = 260;  // halves per t-row in staging LDS (520 B: 8B-aligned, bank-spread)

// ---- k_pre: blocks [0,1024) = BN1 stats + coalesced fp16 transpose of x;
//             blocks [1024,1408) = weight fragment swizzle; block 1408 = u/v/c prep ----
__global__ __launch_bounds__(256) void k_pre(const float* __restrict__ x,
                                             const float* __restrict__ g1,
                                             const float* __restrict__ b1,
                                             const float* __restrict__ Wih,
                                             const float* __restrict__ Whh,
                                             const float* __restrict__ Wt,
                                             const float* __restrict__ bt,
                                             const float* __restrict__ a,
                                             float* __restrict__ ws) {
    int b = blockIdx.x;
    int tid = threadIdx.x;
    if (b >= 1024) {
        if (b == 1408) {
            int k = tid;
            if (k < HH) {
                float u1 = 0.f, u2 = 0.f;
                for (int j = 0; j < HH; j++) {
                    float w = Wt[j * HH + k];
                    u1 = fmaf(w, a[j], u1);
                    u2 = fmaf(w, a[HH + j], u2);
                }
                ws[U1O + k] = u1;
                ws[U2O + k] = u2;
                if (k == 0) {
                    float c1 = 0.f, c2 = 0.f;
                    for (int j = 0; j < HH; j++) {
                        c1 = fmaf(bt[j], a[j], c1);
                        c2 = fmaf(bt[j], a[HH + j], c2);
                    }
                    ws[CCO] = c1;
                    ws[CCO + 1] = c2;
                    ((unsigned*)ws)[CCO + 2] = fenc_(-1e30f);
                }
            }
            return;
        }
        // weight swizzle: frag (w,g,ks): W[k][col], col=g*128+w*16+(lane&15), k=ks*32+(lane>>4)*8+j
        int o = (b - 1024) * 256 + tid;
        _Float16* wf = (_Float16*)(ws + WFRG);
        int j = o & 7;
        int lane = (o >> 3) & 63;
        int rest = o >> 9;
        int ks = rest % 6;
        int gw = rest / 6;
        int g = gw & 3, w = gw >> 2;
        int col = g * 128 + w * 16 + (lane & 15);
        int k = ks * 32 + (lane >> 4) * 8 + j;
        float v = (k < DD) ? Wih[col * DD + k] : Whh[col * HH + (k - DD)];
        wf[o] = (_Float16)v;
        return;
    }
    // ---- xstats: rows n0..n0+3; coalesced reads; LDS [t][k] staging; b64 copy-out ----
    __shared__ _Float16 stg[TT * TSTR];     // [t][k], stride 260 halves = 31.2 KB
    __shared__ float rs[256], rss[256];
    __shared__ unsigned done;
    const float4* xb = (const float4*)(x + (size_t)b * 15360);
#pragma unroll
    for (int q = 0; q < 15; q++) {
        int f = q * 256 + tid;
        float4 v = xb[f];
        int k = f / 15, t0 = (f - k * 15) * 4;
        stg[(t0 + 0) * TSTR + k] = (_Float16)v.x;
        stg[(t0 + 1) * TSTR + k] = (_Float16)v.y;
        stg[(t0 + 2) * TSTR + k] = (_Float16)v.z;
        stg[(t0 + 3) * TSTR + k] = (_Float16)v.w;
    }
    __syncthreads();
    {
        int k = tid;   // k = r*64+d, d = k&63
        float s = 0.f, ss = 0.f;
#pragma unroll
        for (int t = 0; t < TT; t++) {
            float v = (float)stg[t * TSTR + k];
            s += v;
            ss = fmaf(v, v, ss);
        }
        rs[tid] = s; rss[tid] = ss;
    }
    __syncthreads();
    if (tid < 64) {
        float ts = rs[tid] + rs[64 + tid] + rs[128 + tid] + rs[192 + tid];
        float tss = rss[tid] + rss[64 + tid] + rss[128 + tid] + rss[192 + tid];
        atomicAdd(&ws[SSUM + tid], ts);
        atomicAdd(&ws[SSUM + 64 + tid], tss);
    }
    __syncthreads();
    if (tid == 0) {
        __threadfence();
        done = atomicAdd((unsigned*)(ws + SSUM) + 128, 1u);
    }
    __syncthreads();
    if (done == 1023u) {
        __threadfence();
        if (tid < 64) {
            float cnt = (float)(NN * TT);
            float m = ws[SSUM + tid] / cnt;
            float var = ws[SSUM + 64 + tid] / cnt - m * m;
            float sc = g1[tid] * rsqrtf(var + 1e-5f);
            ws[SC1 + tid] = sc;
            ws[SH1 + tid] = b1[tid] - m * sc;
        }
    }
    // copy-out: xnT[t][n0..n0+3][0..63]; wave covers one 512B t-chunk per iter
    _Float16* outp = (_Float16*)ws;
    int n0 = b * 4;
    for (int p = tid; p < 3840; p += 256) {
        int t = p >> 6, i = p & 63;
        *(uint2*)(outp + ((size_t)t * NN + n0) * DD + i * 4) =
            *(const uint2*)(stg + t * TSTR + i * 4);
    }
}

// ---- LSTM: MFMA, weights persistent in VGPRs (sc1 fold + bias fold in prologue);
//      epilogue: HID write + BN2 partial sums + last-block BN2 finalize ----
__global__ __launch_bounds__(512, 1) void k_lstm(const float* __restrict__ Wih,
                                                 const float* __restrict__ bih,
                                                 const float* __restrict__ bhh,
                                                 const float* __restrict__ g2,
                                                 const float* __restrict__ b2,
                                                 float* __restrict__ ws) {
    int tid = threadIdx.x;
    int w = tid >> 6, lane = tid & 63;
    int quad = lane >> 4, m = lane & 15;
    int r0 = blockIdx.x * 16;
    __shared__ _Float16 hlds[2][16][136];
    __shared__ float sh1s[64];
    __shared__ float biasl[512];
    __shared__ unsigned dn;
    const _Float16* wf = (const _Float16*)(ws + WFRG);

    h8 bw[4][6];
#pragma unroll
    for (int g = 0; g < 4; g++)
#pragma unroll
        for (int ks = 0; ks < 6; ks++)
            bw[g][ks] = *(const h8*)(wf + ((((w * 4 + g) * 6 + ks) * 64 + lane) * 8));

    if (tid < 64) sh1s[tid] = ws[SH1 + tid];
    for (int p = tid; p < 2 * 16 * 136; p += 512) ((_Float16*)hlds)[p] = (_Float16)0.f;
    __syncthreads();

    // fold sc1 into the x-part (ks 0,1) of the B fragments
    {
        int base = (lane >> 4) * 8;
#pragma unroll
        for (int ks = 0; ks < 2; ks++)
#pragma unroll
            for (int j = 0; j < 8; j++) {
                float sc = ws[SC1 + ks * 32 + base + j];
#pragma unroll
                for (int g = 0; g < 4; g++)
                    bw[g][ks][j] = (_Float16)((float)bw[g][ks][j] * sc);
            }
    }
    // bias fold: biasl[c] = bih[c]+bhh[c] + Wih[c,:]·sh1
    {
        int c = tid;
        float bsum = bih[c] + bhh[c];
        const float4* wr = (const float4*)(Wih + c * 64);
#pragma unroll
        for (int q = 0; q < 16; q++) {
            float4 wv = wr[q];
            bsum = fmaf(wv.x, sh1s[q * 4], fmaf(wv.y, sh1s[q * 4 + 1],
                   fmaf(wv.z, sh1s[q * 4 + 2], fmaf(wv.w, sh1s[q * 4 + 3], bsum))));
        }
        biasl[c] = bsum;
    }
    __syncthreads();
    float bias[4];
#pragma unroll
    for (int g = 0; g < 4; g++) bias[g] = biasl[g * 128 + w * 16 + m];

    f4 cst = {};
    float hv[4];
    const _Float16* xb = (const _Float16*)ws + (size_t)(r0 + m) * DD + quad * 8;

    h8 ax0 = *(const h8*)xb;
    h8 ax1 = *(const h8*)(xb + 32);

    for (int t = 0; t < TT; t++) {
        h8 ah[4];
        const _Float16* hb = &hlds[(t + 1) & 1][m][quad * 8];
#pragma unroll
        for (int ks = 0; ks < 4; ks++) ah[ks] = *(const h8*)(hb + ks * 32);
        h8 nx0 = {}, nx1 = {};
        if (t + 1 < TT) {
            const _Float16* xp = xb + (size_t)(t + 1) * NN * DD;
            nx0 = *(const h8*)xp;
            nx1 = *(const h8*)(xp + 32);
        }

        f4 acc[4];
#pragma unroll
        for (int g = 0; g < 4; g++) acc[g] = (f4){bias[g], bias[g], bias[g], bias[g]};
#pragma unroll
        for (int g = 0; g < 4; g++) acc[g] = __builtin_amdgcn_mfma_f32_16x16x32_f16(ax0, bw[g][0], acc[g], 0, 0, 0);
#pragma unroll
        for (int g = 0; g < 4; g++) acc[g] = __builtin_amdgcn_mfma_f32_16x16x32_f16(ax1, bw[g][1], acc[g], 0, 0, 0);
#pragma unroll
        for (int ks = 0; ks < 4; ks++)
#pragma unroll
            for (int g = 0; g < 4; g++)
                acc[g] = __builtin_amdgcn_mfma_f32_16x16x32_f16(ah[ks], bw[g][ks + 2], acc[g], 0, 0, 0);

#pragma unroll
        for (int r = 0; r < 4; r++) {
            float ig = sigmoidf_(acc[0][r]);
            float fg = sigmoidf_(acc[1][r]);
            float gg = tanhfast_(acc[2][r]);
            float og = sigmoidf_(acc[3][r]);
            float c = fmaf(fg, cst[r], ig * gg);
            cst[r] = c;
            hv[r] = og * tanhfast_(c);
        }
        _Float16* wbuf = &hlds[t & 1][0][0];
        int col = w * 16 + m;
#pragma unroll
        for (int r = 0; r < 4; r++) wbuf[(quad * 4 + r) * 136 + col] = (_Float16)hv[r];
        __syncthreads();
        ax0 = nx0; ax1 = nx1;
    }
    int col = w * 16 + m;
#pragma unroll
    for (int r = 0; r < 4; r++)
        ws[HID + (size_t)(r0 + quad * 4 + r) * HH + col] = hv[r];

    // BN2 partial sums (wave-local reduce over the 16 rows, then 1 atomic/col)
    float s = hv[0] + hv[1] + hv[2] + hv[3];
    float ss = fmaf(hv[0], hv[0], fmaf(hv[1], hv[1], fmaf(hv[2], hv[2], hv[3] * hv[3])));
    s += __shfl_xor(s, 16, 64); s += __shfl_xor(s, 32, 64);
    ss += __shfl_xor(ss, 16, 64); ss += __shfl_xor(ss, 32, 64);
    if (quad == 0) {
        atomicAdd(&ws[SSUM + 132 + col], s);
        atomicAdd(&ws[SSUM + 260 + col], ss);
    }
    __syncthreads();
    if (tid == 0) {
        __threadfence();
        dn = atomicAdd((unsigned*)(ws + SSUM) + 129, 1u);
    }
    __syncthreads();
    if (dn == 255u) {
        __threadfence();
        if (tid < 128) {
            float mm = ws[SSUM + 132 + tid] / (float)NN;
            float var = ws[SSUM + 260 + tid] / (float)NN - mm * mm;
            float sc = g2[tid] * rsqrtf(var + 1e-5f);
            ws[SC2 + tid] = sc;
            ws[SH2 + tid] = b2[tid] - mm * sc;
        }
    }
}

// ---- apply BN2: s1, s2, fp32 hbn, LDS-staged coalesced swizzled fp16 hbn, s1max ----
__global__ void k_hbn(float* __restrict__ ws) {
    __shared__ float sc[HH], sh[HH], u1s[HH], u2s[HH];
    __shared__ _Float16 swz[4096];
    int tid = threadIdx.x;
    if (tid < HH) {
        sc[tid] = ws[SC2 + tid]; sh[tid] = ws[SH2 + tid];
        u1s[tid] = ws[U1O + tid]; u2s[tid] = ws[U2O + tid];
    }
    __syncthreads();
    int r = tid >> 3, l = tid & 7;
    int n = blockIdx.x * 32 + r;
    const float* hr = ws + HID + (size_t)n * HH;
    float* hb = ws + HBN + (size_t)n * HH;
    int lanehi = (r >> 3);
    int jj = r & 7;
    float d1 = 0.f, d2 = 0.f;
    int k0 = l * 16;
#pragma unroll
    for (int q4 = 0; q4 < 4; q4++) {
        float4 hv4 = *(const float4*)&hr[k0 + q4 * 4];
        float4 o;
#pragma unroll
        for (int c = 0; c < 4; c++) {
            int kk = k0 + q4 * 4 + c;
            float v = fmaf(((const float*)&hv4)[c], sc[kk], sh[kk]);
            ((float*)&o)[c] = v;
            swz[l * 512 + (lanehi * 16 + (kk & 15)) * 8 + jj] = (_Float16)v;
            d1 = fmaf(v, u1s[kk], d1);
            d2 = fmaf(v, u2s[kk], d2);
        }
        *(float4*)&hb[k0 + q4 * 4] = o;
    }
#pragma unroll
    for (int o = 1; o < 8; o <<= 1) { d1 += __shfl_xor(d1, o, 64); d2 += __shfl_xor(d2, o, 64); }
    if (l == 0) {
        float s1 = d1 + ws[CCO];
        ws[S1O + n] = s1;
        ws[S2O + n] = d2 + ws[CCO + 1];
        atomicMax((unsigned*)ws + CCO + 2, fenc_(s1));
    }
    __syncthreads();
    _Float16* dst = (_Float16*)ws + (size_t)blockIdx.x * 4096;
    for (int p = tid; p < 512; p += 256)
        *(h8*)(dst + p * 8) = *(const h8*)(swz + p * 8);
}

// ---- attention + fc fused ----
__global__ __launch_bounds__(512, 1) void k_attfc(const float* __restrict__ Wfc,
                                                  const float* __restrict__ bfc,
                                                  const float* __restrict__ Wout,
                                                  const float* __restrict__ bout,
                                                  float* __restrict__ ws,
                                                  float* __restrict__ out) {
    __shared__ float ls1[NN];
    __shared__ float h2s[16][132];
    int tid = threadIdx.x;
    int w = tid >> 6, lane = tid & 63;
    int quad = lane >> 4, m = lane & 15;
    int n0 = blockIdx.x * 16;
    for (int i = tid; i < NN; i += 512) ls1[i] = ws[S1O + i];
    __syncthreads();
    float s1max = fdec_(((unsigned*)ws)[CCO + 2]);
    float s2n = ws[S2O + n0 + m];
    float mi = leakyf_(s2n + s1max);
    const _Float16* hbsw = (const _Float16*)ws;
    int hg = w;
    f4 acc = {};
    float psum = 0.f;
    h8 bcur = *(const h8*)(hbsw + ((size_t)hg * 64 + lane) * 8);
    for (int jt = 0; jt < 128; jt++) {
        const float* sp = &ls1[jt * 32 + quad * 8];
        h8 ap;
        float ps = 0.f;
#pragma unroll
        for (int jj = 0; jj < 8; jj++) {
            float z = s2n + sp[jj];
            float p = __expf(leakyf_(z) - mi);
            ps += p;
            ap[jj] = (_Float16)p;
        }
        psum += ps;
        int jn = (jt + 1 < 128) ? jt + 1 : 127;
        h8 bnext = *(const h8*)(hbsw + ((size_t)(jn * 8 + hg) * 64 + lane) * 8);
        acc = __builtin_amdgcn_mfma_f32_16x16x32_f16(ap, bcur, acc, 0, 0, 0);
        bcur = bnext;
    }
    psum += __shfl_xor(psum, 16, 64);
    psum += __shfl_xor(psum, 32, 64);
    float pinv = 1.f / psum;
    int h = hg * 16 + m;
#pragma unroll
    for (int r = 0; r < 4; r++) {
        int row = quad * 4 + r;
        float inv = __shfl(pinv, row, 64);
        float hbv = ws[HBN + (size_t)(n0 + row) * HH + h];
        h2s[row][h] = fmaf(acc[r], inv, hbv);
    }
    __syncthreads();
    int row = tid >> 5, jj = tid & 31;
    float po = 0.f;
#pragma unroll
    for (int q = 0; q < 4; q++) {
        int j = q * 32 + jj;
        const float4* wr = (const float4*)(Wfc + (size_t)j * HH);
        float a = 0.f;
#pragma unroll 8
        for (int kq = 0; kq < 32; kq++) {
            float4 wv = wr[kq];
            float4 hv = *(const float4*)&h2s[row][kq * 4];
            a = fmaf(wv.x, hv.x, fmaf(wv.y, hv.y, fmaf(wv.z, hv.z, fmaf(wv.w, hv.w, a))));
        }
        po = fmaf(leakyf_(a + bfc[j]), Wout[j], po);
    }
#pragma unroll
    for (int o = 1; o < 32; o <<= 1) po += __shfl_xor(po, o, 64);
    if (jj == 0) out[n0 + row] = 1.f / (1.f + __expf(-(po + bout[0])));
}

extern "C" void kernel_launch(void* const* d_in, const int* in_sizes, int n_in,
                              void* d_out, int out_size, void* d_ws, size_t ws_size,
                              hipStream_t stream) {
    const float* x = (const float*)d_in[0];
    const float* bn1_g = (const float*)d_in[1];
    const float* bn1_b = (const float*)d_in[2];
    const float* W_ih = (const float*)d_in[3];
    const float* W_hh = (const float*)d_in[4];
    const float* b_ih = (const float*)d_in[5];
    const float* b_hh = (const float*)d_in[6];
    const float* bn2_g = (const float*)d_in[7];
    const float* bn2_b = (const float*)d_in[8];
    const float* W_t = (const float*)d_in[9];
    const float* b_t = (const float*)d_in[10];
    const float* a = (const float*)d_in[11];
    const float* W_fc = (const float*)d_in[12];
    const float* b_fc = (const float*)d_in[13];
    const float* W_out = (const float*)d_in[14];
    const float* b_out = (const float*)d_in[15];
    float* ws = (float*)d_ws;
    float* out = (float*)d_out;

    hipMemsetAsync((char*)d_ws + SSUM * sizeof(float), 0, 392 * sizeof(float), stream);
    k_pre<<<1409, 256, 0, stream>>>(x, bn1_g, bn1_b, W_ih, W_hh, W_t, b_t, a, ws);
    k_lstm<<<NN / 16, 512, 0, stream>>>(W_ih, b_ih, b_hh, bn2_g, bn2_b, ws);
    k_hbn<<<NN / 32, 256, 0, stream>>>(ws);
    k_attfc<<<NN / 16, 512, 0, stream>>>(W_fc, b_fc, W_out, b_out, ws, out);
}